// Round 5
// baseline (202.184 us; speedup 1.0000x reference)
//
#include <hip/hip_runtime.h>
#include <stdint.h>

#define NB 4
#define CC 256
#define NN 4096   // H*W = 64*64
#define KITERS 32 // k-steps per attention chunk (chunk = 1024)
#define WAIT_LGKM0 0xC07F  // s_waitcnt lgkmcnt(0), vmcnt/expcnt untouched

typedef __attribute__((ext_vector_type(8))) _Float16 half8;   // MFMA A/B frag (4 VGPR)
typedef __attribute__((ext_vector_type(4))) _Float16 half4;   // 8B packed store
typedef __attribute__((ext_vector_type(2))) _Float16 half2v;
typedef __attribute__((ext_vector_type(4))) float floatx4;    // 16x16 acc
typedef __attribute__((ext_vector_type(16))) float float16v;  // 32x32 acc
typedef __attribute__((ext_vector_type(4))) int intx4;        // 16B copy

__device__ __forceinline__ void cvt16v(float4 a, float4 b, float4 c, float4 d,
                                       half8& lo, half8& hi) {
  lo[0] = (_Float16)a.x; lo[1] = (_Float16)a.y; lo[2] = (_Float16)a.z; lo[3] = (_Float16)a.w;
  lo[4] = (_Float16)b.x; lo[5] = (_Float16)b.y; lo[6] = (_Float16)b.z; lo[7] = (_Float16)b.w;
  hi[0] = (_Float16)c.x; hi[1] = (_Float16)c.y; hi[2] = (_Float16)c.z; hi[3] = (_Float16)c.w;
  hi[4] = (_Float16)d.x; hi[5] = (_Float16)d.y; hi[6] = (_Float16)d.z; hi[7] = (_Float16)d.w;
}

// pack two f32 -> one u32 of two f16 (RTE, identical to scalar casts)
__device__ __forceinline__ int packh2(float a, float b) {
  half2v p; p[0] = (_Float16)a; p[1] = (_Float16)b;
  return __builtin_bit_cast(int, p);
}

// async global->LDS, 16B per lane; lds dest = wave-uniform base + lane*16.
// PROVEN FORM (R1/R4): global side cast via uintptr, LDS side cast DIRECTLY
// from the generic pointer (compiler emits a correct addrspacecast).
// PITFALL (R2): casting the LDS generic pointer through uintptr_t to
// addrspace(3) reinterprets the FLAT address as an LDS offset -> garbage.
__device__ __forceinline__ void a16(const _Float16* g, _Float16* l) {
  __builtin_amdgcn_global_load_lds(
      (__attribute__((address_space(1))) void*)(uintptr_t)g,
      (__attribute__((address_space(3))) void*)l, 16, 0, 0);
}
__device__ __forceinline__ void a16f(const float* g, float* l) {
  __builtin_amdgcn_global_load_lds(
      (__attribute__((address_space(1))) void*)(uintptr_t)g,
      (__attribute__((address_space(3))) void*)l, 16, 0, 0);
}

// ---------------------------------------------------------------------------
// Fused transpose + Q/K/V projections -> FRAG-MAJOR (swizzled) outputs. v13:
//  - F tile staged via global_load_lds into dbuf fp32 tmp[2][32][128] (no reg
//    roundtrip; DMA dest is linear per-wave rows 8w..8w+7; per-lane global
//    src row 2rr+(lane>>5), col (lane&31)*4 matches the linear dest exactly).
//  - Barriers 3 -> 2 per k-iter: __syncthreads at top (vmcnt(0) drain = DMA
//    arrival point, one full iteration in flight), raw lgkmcnt(0)+s_barrier
//    before MFMA (vm untouched: DMAs + W prefetch stay in flight).
//  - W slice loaded AFTER the second barrier -> hides under the MFMA phase,
//    drains at next-iter __syncthreads.
//  Transposed read tmp[buf][xh+i][xr]: bank = xr&31, 32 banks 2-way = free.
//  Arithmetic bit-identical to R1 (same bytes, same cvt, same MFMA order).
// z=0: Q = Wf.Fc   z=1: K = Wg.Fs   z=2: Vt = (Fs^T.Wh^T)^T
// grid (64, NB, 3), 256 threads, 3 blocks/CU (52 KB LDS).
// ---------------------------------------------------------------------------
__global__ __launch_bounds__(256, 3) void k_qkv(const float* __restrict__ Fc,
                                                const float* __restrict__ Fs,
                                                const float* __restrict__ Wf,
                                                const float* __restrict__ Wg,
                                                const float* __restrict__ Wh,
                                                const float* __restrict__ bf,
                                                const float* __restrict__ bg,
                                                const float* __restrict__ bh,
                                                _Float16* __restrict__ Qs,
                                                _Float16* __restrict__ Ks,
                                                _Float16* __restrict__ Vs) {
  __shared__ float tmp[2][32][128];  // 32 KB fp32 transpose staging (DMA dbuf)
  __shared__ _Float16 As[128][40];   // 10 KB
  __shared__ _Float16 Bs[128][40];   // 10 KB
  const int z = blockIdx.z, bz = blockIdx.y;
  const float* F = ((z == 0) ? Fc : Fs) + (size_t)bz * CC * NN;
  const float* W = (z == 0) ? Wf : ((z == 1) ? Wg : Wh);
  const float* bias = (z == 0) ? bf : ((z == 1) ? bg : bh);
  int mt, nt;
  if (z < 2) { mt = blockIdx.x >> 5; nt = blockIdx.x & 31; }  // M=d(256), N=n(4096)
  else       { mt = blockIdx.x >> 1; nt = blockIdx.x & 1;  }  // M=n(4096), N=d(256)
  const int m0 = mt * 128, n0 = nt * 128;
  const int xn0 = (z < 2) ? n0 : m0;  // spatial base of the F tile (X side)
  const int wd0 = (z < 2) ? m0 : n0;  // W row base (channel side)
  const int tid = threadIdx.x;
  const int wave = tid >> 6, lane = tid & 63, quad = lane >> 4, l15 = lane & 15;
  const int wm = (wave >> 1) * 64, wn = (wave & 1) * 64;

  floatx4 acc[4][4];
#pragma unroll
  for (int i = 0; i < 4; i++)
#pragma unroll
    for (int j = 0; j < 4; j++) acc[i][j] = (floatx4){0.f, 0.f, 0.f, 0.f};

  const int srow = tid >> 1, shalf = (tid & 1) * 16;   // W staging
  const int xr = tid >> 1, xh = (tid & 1) * 16;        // transposed read
  const int fcol = (lane & 31) * 4;                    // DMA source column (floats)
  const int frh = lane >> 5;                           // DMA source row half

  float4 wr0, wr1, wr2, wr3;
  {
#pragma unroll
    for (int p = 0; p < 4; p++) {
      const int rr = 4 * wave + p;
      a16f(F + (size_t)(2 * rr + frh) * NN + xn0 + fcol, &tmp[0][0][0] + rr * 256);
    }
    const float4* wp = (const float4*)(W + (size_t)(wd0 + srow) * 256 + 0 + shalf);
    wr0 = wp[0]; wr1 = wp[1]; wr2 = wp[2]; wr3 = wp[3];
  }

  for (int kk = 0; kk < 256; kk += 32) {
    const int buf = (kk >> 5) & 1;
    // #1: per-wave vmcnt(0) drain (tmp[buf] DMA + W regs landed) + barrier;
    // also guarantees all waves' prev-iter frag/tmp reads are done.
    __syncthreads();
    if (kk + 32 < 256) {  // DMA next F slice into the other buffer (full-iter window)
#pragma unroll
      for (int p = 0; p < 4; p++) {
        const int rr = 4 * wave + p;
        a16f(F + (size_t)(kk + 32 + 2 * rr + frh) * NN + xn0 + fcol,
             &tmp[buf ^ 1][0][0] + rr * 256);
      }
    }
    half8 w_lo, w_hi;
    cvt16v(wr0, wr1, wr2, wr3, w_lo, w_hi);
    if (z < 2) {
      *(half8*)&As[srow][shalf] = w_lo;
      *(half8*)&As[srow][shalf + 8] = w_hi;
    } else {
      *(half8*)&Bs[srow][shalf] = w_lo;
      *(half8*)&Bs[srow][shalf + 8] = w_hi;
    }
    half8 xlo, xhi;
#pragma unroll
    for (int i = 0; i < 8; i++) xlo[i] = (_Float16)tmp[buf][xh + i][xr];
#pragma unroll
    for (int i = 0; i < 8; i++) xhi[i] = (_Float16)tmp[buf][xh + 8 + i][xr];
    if (z < 2) {
      *(half8*)&Bs[xr][xh] = xlo;
      *(half8*)&Bs[xr][xh + 8] = xhi;
    } else {
      *(half8*)&As[xr][xh] = xlo;
      *(half8*)&As[xr][xh + 8] = xhi;
    }
    // #2: flush own ds_writes, then barrier. vmcnt untouched: this iter's
    // DMAs stay in flight across the MFMA phase.
    asm volatile("s_waitcnt lgkmcnt(0)" ::: "memory");
    asm volatile("s_barrier" ::: "memory");
    if (kk + 32 < 256) {  // W slice for next iter: hides under MFMA phase
      const float4* wp = (const float4*)(W + (size_t)(wd0 + srow) * 256 + kk + 32 + shalf);
      wr0 = wp[0]; wr1 = wp[1]; wr2 = wp[2]; wr3 = wp[3];
    }
    half8 af[4], bfr[4];
#pragma unroll
    for (int mb = 0; mb < 4; mb++) af[mb] = *(const half8*)&As[wm + mb * 16 + l15][quad * 8];
#pragma unroll
    for (int nb = 0; nb < 4; nb++) bfr[nb] = *(const half8*)&Bs[wn + nb * 16 + l15][quad * 8];
#pragma unroll
    for (int mb = 0; mb < 4; mb++)
#pragma unroll
      for (int nb = 0; nb < 4; nb++)
        acc[mb][nb] = __builtin_amdgcn_mfma_f32_16x16x32_f16(af[mb], bfr[nb], acc[mb][nb], 0, 0, 0);
  }

  if (z < 2) {
    _Float16* op = (z == 0 ? Qs : Ks) + (size_t)bz * NN * CC;
#pragma unroll
    for (int mb = 0; mb < 4; mb++) {
      int d0 = m0 + wm + mb * 16 + quad * 4;
      float b0 = bias[d0], b1 = bias[d0 + 1], b2 = bias[d0 + 2], b3 = bias[d0 + 3];
      const int cs = d0 >> 4, hh = (d0 >> 3) & 1, j0 = d0 & 7;
#pragma unroll
      for (int nb = 0; nb < 4; nb++) {
        int n_ = n0 + wn + nb * 16 + l15;
        int kt = n_ >> 5, ql_ = n_ & 31;
        half4 pk;
        pk[0] = (_Float16)(acc[mb][nb][0] + b0);
        pk[1] = (_Float16)(acc[mb][nb][1] + b1);
        pk[2] = (_Float16)(acc[mb][nb][2] + b2);
        pk[3] = (_Float16)(acc[mb][nb][3] + b3);
        size_t idx = ((size_t)(kt * 16 + cs) * 64 + ql_ + 32 * hh) * 8 + j0;
        *(half4*)(op + idx) = pk;
      }
    }
  } else {
    _Float16* op = Vs + (size_t)bz * NN * CC;
#pragma unroll
    for (int mb = 0; mb < 4; mb++) {
      int nq0 = m0 + wm + mb * 16 + quad * 4;
      const int kt = nq0 >> 5, krel = nq0 & 31;
      const int hk = krel >> 4, hh = (krel >> 3) & 1, j0 = krel & 7;
#pragma unroll
      for (int nb = 0; nb < 4; nb++) {
        int d = n0 + wn + nb * 16 + l15;
        int ql_ = d & 31, g = (d >> 5) & 7;
        float bv = bias[d];
        half4 pk;
        pk[0] = (_Float16)(acc[mb][nb][0] + bv);
        pk[1] = (_Float16)(acc[mb][nb][1] + bv);
        pk[2] = (_Float16)(acc[mb][nb][2] + bv);
        pk[3] = (_Float16)(acc[mb][nb][3] + bv);
        size_t idx = (((size_t)(kt * 8 + g) * 2 + hk) * 64 + ql_ + 32 * hh) * 8 + j0;
        *(half4*)(op + idx) = pk;
      }
    }
  }
}

// ---------------------------------------------------------------------------
// Flash attention v9 (R1-exact, harness-verified at 83.6 us):
// global_load_lds K/V dbuf, 1 barrier/iter, in-register P via
// cvt_pk+permlane32_swap (DISTINCT operands only — R3 pitfall), setprio.
// Stagger removed (R4: neutral-to-negative).
// grid (32 qtiles, 4 chunks, NB), 256 threads.
// ---------------------------------------------------------------------------
__global__ __launch_bounds__(256, 2) void k_attn(const _Float16* __restrict__ Q,
                                                 const _Float16* __restrict__ K,
                                                 const _Float16* __restrict__ Vt,
                                                 _Float16* __restrict__ Opart,
                                                 float2* __restrict__ Ml) {
  __shared__ _Float16 smem[8192 * 4];  // K dbuf 32KB | V dbuf 32KB
  const int tid = threadIdx.x;
  const int wave = tid >> 6, lane = tid & 63;

  const int qt = blockIdx.x, ck = blockIdx.y, b = blockIdx.z;
  const int ql = lane & 31, h = lane >> 5;
  const int q0 = qt * 128 + wave * 32;
  const _Float16* Qb = Q + (size_t)b * NN * CC;
  const _Float16* Kg = K + (size_t)b * NN * CC;
  const _Float16* Vg = Vt + (size_t)b * NN * CC;
  const int kt_base = ck * KITERS;
  const int so = wave * 512;             // per-wave LDS stage base (halves)
  const int go = wave * 512 + lane * 8;  // per-lane global offset (halves)

  const int ktq = q0 >> 5;
  half8 qf[16];
#pragma unroll
  for (int cs = 0; cs < 16; cs++)
    qf[cs] = *(const half8*)(Qb + ((size_t)(ktq * 16 + cs) * 64 + lane) * 8);

  float16v Oa[8];
#pragma unroll
  for (int g = 0; g < 8; g++)
#pragma unroll
    for (int i = 0; i < 16; i++) Oa[g][i] = 0.f;

  float m_run = -1e30f, l_run = 0.f;
  half8 pf0, pf1;  // previous-iter P fragments, live in registers
#pragma unroll
  for (int i = 0; i < 8; i++) { pf0[i] = (_Float16)0.f; pf1[i] = (_Float16)0.f; }

  // prologue: stage K[0] -> Kbuf0
  {
    const _Float16* Kt = Kg + (size_t)kt_base * 8192;
#pragma unroll
    for (int p = 0; p < 4; p++) a16(Kt + p * 2048 + go, smem + p * 2048 + so);
  }

  for (int t = 0; t < KITERS; t++) {
    asm volatile("s_waitcnt vmcnt(0)" ::: "memory");  // K[t] (+V[t-1]) landed
    __builtin_amdgcn_s_barrier();
    // stage V[t] -> Vbuf[t&1]; K[t+1] -> Kbuf[(t+1)&1]
    // (targets were last read in iter t-1: ordered by the barrier above)
    {
      const _Float16* Vtile = Vg + (size_t)(kt_base + t) * 8192;
      _Float16* Vw = smem + (2 + (t & 1)) * 8192;
#pragma unroll
      for (int p = 0; p < 4; p++) a16(Vtile + p * 2048 + go, Vw + p * 2048 + so);
      if (t + 1 < KITERS) {
        const _Float16* Kt = Kg + (size_t)(kt_base + t + 1) * 8192;
        _Float16* Kw = smem + ((t + 1) & 1) * 8192;
#pragma unroll
        for (int p = 0; p < 4; p++) a16(Kt + p * 2048 + go, Kw + p * 2048 + so);
      }
    }
    const _Float16* Kl = smem + (t & 1) * 8192;

    // ---- MFMA burst: S_i and PV_i interleaved; PV in ks-outer order:
    //   i<8: Oa[i]   += V[2i]  ·pf0     i>=8: Oa[i-8] += V[2(i-8)+1]·pf1
    float16v s, s2;
#pragma unroll
    for (int i = 0; i < 16; i++) { s[i] = 0.f; s2[i] = 0.f; }
    __builtin_amdgcn_s_setprio(1);
    if (t > 0) {
      const _Float16* Vr = smem + (2 + ((t - 1) & 1)) * 8192;
#pragma unroll
      for (int i = 0; i < 16; i++) {
        half8 kf = *(const half8*)(Kl + i * 512 + lane * 8);
        if (i & 1)
          s2 = __builtin_amdgcn_mfma_f32_32x32x16_f16(kf, qf[i], s2, 0, 0, 0);
        else
          s = __builtin_amdgcn_mfma_f32_32x32x16_f16(kf, qf[i], s, 0, 0, 0);
        const int u = i & 7, ks = i >> 3;
        half8 vf = *(const half8*)(Vr + (2 * u + ks) * 512 + lane * 8);
        Oa[u] = __builtin_amdgcn_mfma_f32_32x32x16_f16(vf, ks ? pf1 : pf0, Oa[u], 0, 0, 0);
      }
    } else {
#pragma unroll
      for (int cs = 0; cs < 16; cs += 2) {
        half8 kfa = *(const half8*)(Kl + cs * 512 + lane * 8);
        s = __builtin_amdgcn_mfma_f32_32x32x16_f16(kfa, qf[cs], s, 0, 0, 0);
        half8 kfb = *(const half8*)(Kl + (cs + 1) * 512 + lane * 8);
        s2 = __builtin_amdgcn_mfma_f32_32x32x16_f16(kfb, qf[cs + 1], s2, 0, 0, 0);
      }
    }
    __builtin_amdgcn_s_setprio(0);
#pragma unroll
    for (int i = 0; i < 16; i++) s[i] += s2[i];

    // ---- lazy online softmax (per-lane), tree reductions
    float t0 = fmaxf(s[0], s[1]), t1 = fmaxf(s[2], s[3]);
    float t2 = fmaxf(s[4], s[5]), t3 = fmaxf(s[6], s[7]);
    float t4 = fmaxf(s[8], s[9]), t5 = fmaxf(s[10], s[11]);
    float t6 = fmaxf(s[12], s[13]), t7 = fmaxf(s[14], s[15]);
    t0 = fmaxf(t0, t1); t2 = fmaxf(t2, t3); t4 = fmaxf(t4, t5); t6 = fmaxf(t6, t7);
    float tmax = fmaxf(fmaxf(t0, t2), fmaxf(t4, t6));
    tmax = fmaxf(tmax, __shfl_xor(tmax, 32));
    bool need = tmax > m_run + 8.0f;
    if (__any((int)need)) {
      float mN = need ? tmax : m_run;
      float alpha = __expf(m_run - mN);
      m_run = mN;
      l_run *= alpha;
#pragma unroll
      for (int g = 0; g < 8; g++)
#pragma unroll
        for (int i = 0; i < 16; i++) Oa[g][i] *= alpha;
    }
#pragma unroll
    for (int i = 0; i < 16; i++) s[i] = __expf(s[i] - m_run);
    float u0 = (s[0] + s[1]) + (s[2] + s[3]);
    float u1 = (s[4] + s[5]) + (s[6] + s[7]);
    float u2 = (s[8] + s[9]) + (s[10] + s[11]);
    float u3 = (s[12] + s[13]) + (s[14] + s[15]);
    float ts = (u0 + u1) + (u2 + u3);
    ts += __shfl_xor(ts, 32);
    l_run += ts;

    // ---- P -> registers: pack f16 pairs, swap halves across lane 32 boundary.
    // acc row map: rows(i) = (i&3) + 8*(i>>2) + 4h; B-frag needs row 8h+j (pf0)
    // and 16+8h+j (pf1) at col=ql. (distinct-operand permlane only)
    {
      int A01 = packh2(s[0], s[1]), B23 = packh2(s[2], s[3]);
      int C45 = packh2(s[4], s[5]), D67 = packh2(s[6], s[7]);
      int E01 = packh2(s[8], s[9]), F23 = packh2(s[10], s[11]);
      int G45 = packh2(s[12], s[13]), H67 = packh2(s[14], s[15]);
      auto rA = __builtin_amdgcn_permlane32_swap(A01, C45, false, false);
      auto rB = __builtin_amdgcn_permlane32_swap(B23, D67, false, false);
      auto rC = __builtin_amdgcn_permlane32_swap(E01, G45, false, false);
      auto rD = __builtin_amdgcn_permlane32_swap(F23, H67, false, false);
      intx4 w0, w1;
      w0[0] = rA[0]; w0[1] = rB[0]; w0[2] = rA[1]; w0[3] = rB[1];
      w1[0] = rC[0]; w1[1] = rD[0]; w1[2] = rC[1]; w1[3] = rD[1];
      pf0 = __builtin_bit_cast(half8, w0);
      pf1 = __builtin_bit_cast(half8, w1);
    }
  }

  // ---- tail: PV for last tile (ks-outer, same per-chain order)
  asm volatile("s_waitcnt vmcnt(0)" ::: "memory");  // V[KITERS-1] landed
  __builtin_amdgcn_s_barrier();
  {
    const _Float16* Vr = smem + (2 + ((KITERS - 1) & 1)) * 8192;
#pragma unroll
    for (int u = 0; u < 8; u++) {
      half8 vfa = *(const half8*)(Vr + (2 * u) * 512 + lane * 8);
      Oa[u] = __builtin_amdgcn_mfma_f32_32x32x16_f16(vfa, pf0, Oa[u], 0, 0, 0);
    }
#pragma unroll
    for (int u = 0; u < 8; u++) {
      half8 vfb = *(const half8*)(Vr + (2 * u + 1) * 512 + lane * 8);
      Oa[u] = __builtin_amdgcn_mfma_f32_32x32x16_f16(vfb, pf1, Oa[u], 0, 0, 0);
    }
  }

  // ---- epilogue: normalize, per-wave LDS transpose, coalesced store
  float invl = 1.f / l_run;
  __syncthreads();
  float* ot = (float*)smem + wave * (32 * 33);
  _Float16* Opb = Opart + ((size_t)ck * NB + b) * NN * CC;
  const int qr = lane >> 1;
  const int chalf = (lane & 1) * 16;
#pragma unroll
  for (int g = 0; g < 8; g++) {
#pragma unroll
    for (int r = 0; r < 16; r++)
      ot[((r & 3) + 8 * (r >> 2) + 4 * h) * 33 + ql] = Oa[g][r] * invl;
    __builtin_amdgcn_s_waitcnt(WAIT_LGKM0);
    half8 o0, o1;
#pragma unroll
    for (int i = 0; i < 8; i++) o0[i] = (_Float16)ot[(chalf + i) * 33 + qr];
#pragma unroll
    for (int i = 0; i < 8; i++) o1[i] = (_Float16)ot[(chalf + 8 + i) * 33 + qr];
    _Float16* gp = Opb + (size_t)(q0 + qr) * CC + g * 32 + chalf;
    *(half8*)gp = o0;
    *(half8*)(gp + 8) = o1;
    __builtin_amdgcn_s_waitcnt(WAIT_LGKM0);
  }
  if (h == 0) {
    float2 ml; ml.x = m_run; ml.y = l_run;
    Ml[((size_t)ck * NB + b) * NN + q0 + ql] = ml;
  }
}

// ---------------------------------------------------------------------------
// Final conv with fused split-K merge, re-tiled 64x128 for 2 blocks/CU.
// out[b][d][n] fp32 = Wo . O^T + bo. grid (128, NB), 256 threads. (unchanged)
// ---------------------------------------------------------------------------
__global__ __launch_bounds__(256, 2) void k_out(const _Float16* __restrict__ Opart,
                                                const float2* __restrict__ Ml,
                                                const float* __restrict__ Wo,
                                                const float* __restrict__ bo,
                                                float* __restrict__ out) {
  __shared__ _Float16 As[64][40];    // 5 KB  (merged O rows)
  __shared__ _Float16 Bs[128][40];   // 10 KB (Wo rows)
  const int bz = blockIdx.y;
  const int mt = blockIdx.x >> 1, nt = blockIdx.x & 1;  // 64 mtiles x 2 ntiles
  const int m0 = mt * 64, n0 = nt * 128;
  const int tid = threadIdx.x;
  const int wave = tid >> 6, lane = tid & 63, quad = lane >> 4, l15 = lane & 15;
  const int wn = wave * 32;

  floatx4 acc[4][2];
#pragma unroll
  for (int i = 0; i < 4; i++)
#pragma unroll
    for (int j = 0; j < 2; j++) acc[i][j] = (floatx4){0.f, 0.f, 0.f, 0.f};

  const int arow = tid >> 2, acol = (tid & 3) * 8;   // A: 64 rows x 32 c
  const int brow = tid >> 1, bcol = (tid & 1) * 16;  // B: 128 rows x 32 c

  // merge weights for this thread's fixed row q = m0 + arow
  const size_t qi = (size_t)bz * NN + m0 + arow;
  float2 a0 = Ml[qi], a1 = Ml[(size_t)NB * NN + qi];
  float2 a2 = Ml[(size_t)2 * NB * NN + qi], a3 = Ml[(size_t)3 * NB * NN + qi];
  float M = fmaxf(fmaxf(a0.x, a1.x), fmaxf(a2.x, a3.x));
  float w0 = __expf(a0.x - M) * a0.y, w1 = __expf(a1.x - M) * a1.y;
  float w2 = __expf(a2.x - M) * a2.y, w3 = __expf(a3.x - M) * a3.y;
  float inv = 1.f / (w0 + w1 + w2 + w3);
  w0 *= inv; w1 *= inv; w2 *= inv; w3 *= inv;
  const size_t ps = (size_t)NB * NN * CC;
  const _Float16* prow = Opart + qi * CC;

  // preload kk=0
  half8 pA0, pA1, pA2, pA3;
  float4 wr0, wr1, wr2, wr3;
  {
    const _Float16* pr = prow + acol;
    pA0 = *(const half8*)pr;
    pA1 = *(const half8*)(pr + ps);
    pA2 = *(const half8*)(pr + 2 * ps);
    pA3 = *(const half8*)(pr + 3 * ps);
    const float4* wp = (const float4*)(Wo + (size_t)(n0 + brow) * 256 + bcol);
    wr0 = wp[0]; wr1 = wp[1]; wr2 = wp[2]; wr3 = wp[3];
  }

  for (int kk = 0; kk < 256; kk += 32) {
    half8 ma;
#pragma unroll
    for (int i = 0; i < 8; i++)
      ma[i] = (_Float16)(w0 * (float)pA0[i] + w1 * (float)pA1[i] +
                         w2 * (float)pA2[i] + w3 * (float)pA3[i]);
    half8 b_lo, b_hi;
    cvt16v(wr0, wr1, wr2, wr3, b_lo, b_hi);
    __syncthreads();  // prev frag reads done
    *(half8*)&As[arow][acol] = ma;
    *(half8*)&Bs[brow][bcol] = b_lo;
    *(half8*)&Bs[brow][bcol + 8] = b_hi;
    __syncthreads();  // tiles visible
    if (kk + 32 < 256) {  // prefetch next slice
      const _Float16* pr = prow + kk + 32 + acol;
      pA0 = *(const half8*)pr;
      pA1 = *(const half8*)(pr + ps);
      pA2 = *(const half8*)(pr + 2 * ps);
      pA3 = *(const half8*)(pr + 3 * ps);
      const float4* wp = (const float4*)(Wo + (size_t)(n0 + brow) * 256 + kk + 32 + bcol);
      wr0 = wp[0]; wr1 = wp[1]; wr2 = wp[2]; wr3 = wp[3];
    }
    half8 af[4], bfr[2];
#pragma unroll
    for (int mb = 0; mb < 4; mb++) af[mb] = *(const half8*)&As[mb * 16 + l15][quad * 8];
#pragma unroll
    for (int nb = 0; nb < 2; nb++) bfr[nb] = *(const half8*)&Bs[wn + nb * 16 + l15][quad * 8];
#pragma unroll
    for (int mb = 0; mb < 4; mb++)
#pragma unroll
      for (int nb = 0; nb < 2; nb++)
        acc[mb][nb] = __builtin_amdgcn_mfma_f32_16x16x32_f16(af[mb], bfr[nb], acc[mb][nb], 0, 0, 0);
  }

  float* op = out + (size_t)bz * NN * CC;
#pragma unroll
  for (int mb = 0; mb < 4; mb++) {
    int nq0 = m0 + mb * 16 + quad * 4;  // spatial
#pragma unroll
    for (int nb = 0; nb < 2; nb++) {
      int d = n0 + wn + nb * 16 + l15;
      float bv = bo[d];
      floatx4 pk;
      pk[0] = acc[mb][nb][0] + bv;
      pk[1] = acc[mb][nb][1] + bv;
      pk[2] = acc[mb][nb][2] + bv;
      pk[3] = acc[mb][nb][3] + bv;
      *(floatx4*)(op + (size_t)d * NN + nq0) = pk;
    }
  }
}

// ---------------------------------------------------------------------------
extern "C" void kernel_launch(void* const* d_in, const int* in_sizes, int n_in,
                              void* d_out, int out_size, void* d_ws, size_t ws_size,
                              hipStream_t stream) {
  const float* Fc = (const float*)d_in[0];
  const float* Fs = (const float*)d_in[1];
  const float* Wf = (const float*)d_in[2];
  const float* bf_ = (const float*)d_in[3];
  const float* Wg = (const float*)d_in[4];
  const float* bg = (const float*)d_in[5];
  const float* Wh = (const float*)d_in[6];
  const float* bh = (const float*)d_in[7];
  const float* Wo = (const float*)d_in[8];
  const float* bo = (const float*)d_in[9];

  char* ws = (char*)d_ws;
  const size_t sz = (size_t)NB * NN * CC * sizeof(_Float16);  // 8 MB per plane
  _Float16* Opart = (_Float16*)(ws + 0 * sz);  // planes 0..3 (split-K partials)
  _Float16* Qs = (_Float16*)(ws + 4 * sz);     // swizzled
  _Float16* Ks = (_Float16*)(ws + 5 * sz);
  _Float16* Vs = (_Float16*)(ws + 6 * sz);
  float2* Ml = (float2*)(ws + 7 * sz);         // 512 KB

  k_qkv<<<dim3(64, NB, 3), 256, 0, stream>>>(Fc, Fs, Wf, Wg, Wh, bf_, bg, bh, Qs, Ks, Vs);
  k_attn<<<dim3(32, 4, NB), 256, 0, stream>>>(Qs, Ks, Vs, Opart, Ml);
  k_out<<<dim3(128, NB), 256, 0, stream>>>(Opart, Ml, Wo, bo, (float*)d_out);
}

// Round 6
// 195.933 us; speedup vs baseline: 1.0319x; 1.0319x over previous
//
#include <hip/hip_runtime.h>
#include <stdint.h>

#define NB 4
#define CC 256
#define NN 4096   // H*W = 64*64
#define KITERS 32 // k-steps per attention chunk (chunk = 1024)
#define WAIT_LGKM0 0xC07F  // s_waitcnt lgkmcnt(0), vmcnt/expcnt untouched

typedef __attribute__((ext_vector_type(8))) _Float16 half8;   // MFMA A/B frag (4 VGPR)
typedef __attribute__((ext_vector_type(4))) _Float16 half4;   // 8B packed store
typedef __attribute__((ext_vector_type(2))) _Float16 half2v;
typedef __attribute__((ext_vector_type(4))) float floatx4;    // 16x16 acc
typedef __attribute__((ext_vector_type(16))) float float16v;  // 32x32 acc
typedef __attribute__((ext_vector_type(4))) int intx4;        // 16B copy

__device__ __forceinline__ void cvt16v(float4 a, float4 b, float4 c, float4 d,
                                       half8& lo, half8& hi) {
  lo[0] = (_Float16)a.x; lo[1] = (_Float16)a.y; lo[2] = (_Float16)a.z; lo[3] = (_Float16)a.w;
  lo[4] = (_Float16)b.x; lo[5] = (_Float16)b.y; lo[6] = (_Float16)b.z; lo[7] = (_Float16)b.w;
  hi[0] = (_Float16)c.x; hi[1] = (_Float16)c.y; hi[2] = (_Float16)c.z; hi[3] = (_Float16)c.w;
  hi[4] = (_Float16)d.x; hi[5] = (_Float16)d.y; hi[6] = (_Float16)d.z; hi[7] = (_Float16)d.w;
}

// pack two f32 -> one u32 of two f16 (RTE, identical to scalar casts)
__device__ __forceinline__ int packh2(float a, float b) {
  half2v p; p[0] = (_Float16)a; p[1] = (_Float16)b;
  return __builtin_bit_cast(int, p);
}

// async global->LDS, 16B per lane; lds dest = wave-uniform base + lane*16.
// PROVEN FORM (R1/R4): global side cast via uintptr, LDS side cast DIRECTLY
// from the generic pointer. PITFALL (R2): LDS side via uintptr_t reinterprets
// the FLAT address as an LDS offset -> garbage.
__device__ __forceinline__ void a16(const _Float16* g, _Float16* l) {
  __builtin_amdgcn_global_load_lds(
      (__attribute__((address_space(1))) void*)(uintptr_t)g,
      (__attribute__((address_space(3))) void*)l, 16, 0, 0);
}

// ---------------------------------------------------------------------------
// Fused transpose + Q/K/V projections -> FRAG-MAJOR (swizzled) outputs.
// Reads F [b][c][n] fp32 directly; per k-iter transposes 32c x 128n via LDS.
// z=0: Q = Wf.Fc   z=1: K = Wg.Fs   z=2: Vt = (Fs^T.Wh^T)^T
// grid (64, NB, 3), 256 threads, 3 blocks/CU.  (R1-exact, known-good;
// R5's DMA-staging variant measured neutral -> reverted to lowest-risk form)
// ---------------------------------------------------------------------------
__global__ __launch_bounds__(256, 3) void k_qkv(const float* __restrict__ Fc,
                                                const float* __restrict__ Fs,
                                                const float* __restrict__ Wf,
                                                const float* __restrict__ Wg,
                                                const float* __restrict__ Wh,
                                                const float* __restrict__ bf,
                                                const float* __restrict__ bg,
                                                const float* __restrict__ bh,
                                                _Float16* __restrict__ Qs,
                                                _Float16* __restrict__ Ks,
                                                _Float16* __restrict__ Vs) {
  __shared__ float tmp[32][132];     // 16.9 KB fp32 transpose staging
  __shared__ _Float16 As[128][40];   // 10 KB
  __shared__ _Float16 Bs[128][40];   // 10 KB
  const int z = blockIdx.z, bz = blockIdx.y;
  const float* F = ((z == 0) ? Fc : Fs) + (size_t)bz * CC * NN;
  const float* W = (z == 0) ? Wf : ((z == 1) ? Wg : Wh);
  const float* bias = (z == 0) ? bf : ((z == 1) ? bg : bh);
  int mt, nt;
  if (z < 2) { mt = blockIdx.x >> 5; nt = blockIdx.x & 31; }  // M=d(256), N=n(4096)
  else       { mt = blockIdx.x >> 1; nt = blockIdx.x & 1;  }  // M=n(4096), N=d(256)
  const int m0 = mt * 128, n0 = nt * 128;
  const int xn0 = (z < 2) ? n0 : m0;  // spatial base of the F tile (X side)
  const int wd0 = (z < 2) ? m0 : n0;  // W row base (channel side)
  const int tid = threadIdx.x;
  const int wave = tid >> 6, lane = tid & 63, quad = lane >> 4, l15 = lane & 15;
  const int wm = (wave >> 1) * 64, wn = (wave & 1) * 64;

  floatx4 acc[4][4];
#pragma unroll
  for (int i = 0; i < 4; i++)
#pragma unroll
    for (int j = 0; j < 4; j++) acc[i][j] = (floatx4){0.f, 0.f, 0.f, 0.f};

  const int srow = tid >> 1, shalf = (tid & 1) * 16;   // W staging
  const int fc = tid >> 3, fn = (tid & 7) * 16;        // F load (c-row, n-off)
  const int xr = tid >> 1, xh = (tid & 1) * 16;        // transposed read

  float4 wr0, wr1, wr2, wr3, fr0, fr1, fr2, fr3;
  {
    const float4* wp = (const float4*)(W + (size_t)(wd0 + srow) * 256 + 0 + shalf);
    wr0 = wp[0]; wr1 = wp[1]; wr2 = wp[2]; wr3 = wp[3];
    const float4* fp = (const float4*)(F + (size_t)(0 + fc) * NN + xn0 + fn);
    fr0 = fp[0]; fr1 = fp[1]; fr2 = fp[2]; fr3 = fp[3];
  }

  for (int kk = 0; kk < 256; kk += 32) {
    __syncthreads();  // 1: prev frag+tmp reads done
    *(float4*)&tmp[fc][fn + 0] = fr0;
    *(float4*)&tmp[fc][fn + 4] = fr1;
    *(float4*)&tmp[fc][fn + 8] = fr2;
    *(float4*)&tmp[fc][fn + 12] = fr3;
    half8 w_lo, w_hi;
    cvt16v(wr0, wr1, wr2, wr3, w_lo, w_hi);
    if (z < 2) {
      *(half8*)&As[srow][shalf] = w_lo;
      *(half8*)&As[srow][shalf + 8] = w_hi;
    } else {
      *(half8*)&Bs[srow][shalf] = w_lo;
      *(half8*)&Bs[srow][shalf + 8] = w_hi;
    }
    __syncthreads();  // 2: tmp + W-side visible
    if (kk + 32 < 256) {  // prefetch next iter
      const float4* wp = (const float4*)(W + (size_t)(wd0 + srow) * 256 + kk + 32 + shalf);
      wr0 = wp[0]; wr1 = wp[1]; wr2 = wp[2]; wr3 = wp[3];
      const float4* fp = (const float4*)(F + (size_t)(kk + 32 + fc) * NN + xn0 + fn);
      fr0 = fp[0]; fr1 = fp[1]; fr2 = fp[2]; fr3 = fp[3];
    }
    half8 xlo, xhi;
#pragma unroll
    for (int i = 0; i < 8; i++) xlo[i] = (_Float16)tmp[xh + i][xr];
#pragma unroll
    for (int i = 0; i < 8; i++) xhi[i] = (_Float16)tmp[xh + 8 + i][xr];
    if (z < 2) {
      *(half8*)&Bs[xr][xh] = xlo;
      *(half8*)&Bs[xr][xh + 8] = xhi;
    } else {
      *(half8*)&As[xr][xh] = xlo;
      *(half8*)&As[xr][xh + 8] = xhi;
    }
    __syncthreads();  // 3: As/Bs complete
    half8 af[4], bfr[4];
#pragma unroll
    for (int mb = 0; mb < 4; mb++) af[mb] = *(const half8*)&As[wm + mb * 16 + l15][quad * 8];
#pragma unroll
    for (int nb = 0; nb < 4; nb++) bfr[nb] = *(const half8*)&Bs[wn + nb * 16 + l15][quad * 8];
#pragma unroll
    for (int mb = 0; mb < 4; mb++)
#pragma unroll
      for (int nb = 0; nb < 4; nb++)
        acc[mb][nb] = __builtin_amdgcn_mfma_f32_16x16x32_f16(af[mb], bfr[nb], acc[mb][nb], 0, 0, 0);
  }

  if (z < 2) {
    _Float16* op = (z == 0 ? Qs : Ks) + (size_t)bz * NN * CC;
#pragma unroll
    for (int mb = 0; mb < 4; mb++) {
      int d0 = m0 + wm + mb * 16 + quad * 4;
      float b0 = bias[d0], b1 = bias[d0 + 1], b2 = bias[d0 + 2], b3 = bias[d0 + 3];
      const int cs = d0 >> 4, hh = (d0 >> 3) & 1, j0 = d0 & 7;
#pragma unroll
      for (int nb = 0; nb < 4; nb++) {
        int n_ = n0 + wn + nb * 16 + l15;
        int kt = n_ >> 5, ql_ = n_ & 31;
        half4 pk;
        pk[0] = (_Float16)(acc[mb][nb][0] + b0);
        pk[1] = (_Float16)(acc[mb][nb][1] + b1);
        pk[2] = (_Float16)(acc[mb][nb][2] + b2);
        pk[3] = (_Float16)(acc[mb][nb][3] + b3);
        size_t idx = ((size_t)(kt * 16 + cs) * 64 + ql_ + 32 * hh) * 8 + j0;
        *(half4*)(op + idx) = pk;
      }
    }
  } else {
    _Float16* op = Vs + (size_t)bz * NN * CC;
#pragma unroll
    for (int mb = 0; mb < 4; mb++) {
      int nq0 = m0 + wm + mb * 16 + quad * 4;
      const int kt = nq0 >> 5, krel = nq0 & 31;
      const int hk = krel >> 4, hh = (krel >> 3) & 1, j0 = krel & 7;
#pragma unroll
      for (int nb = 0; nb < 4; nb++) {
        int d = n0 + wn + nb * 16 + l15;
        int ql_ = d & 31, g = (d >> 5) & 7;
        float bv = bias[d];
        half4 pk;
        pk[0] = (_Float16)(acc[mb][nb][0] + bv);
        pk[1] = (_Float16)(acc[mb][nb][1] + bv);
        pk[2] = (_Float16)(acc[mb][nb][2] + bv);
        pk[3] = (_Float16)(acc[mb][nb][3] + bv);
        size_t idx = (((size_t)(kt * 8 + g) * 2 + hk) * 64 + ql_ + 32 * hh) * 8 + j0;
        *(half4*)(op + idx) = pk;
      }
    }
  }
}

// ---------------------------------------------------------------------------
// Flash attention v9 (R1-exact, harness-verified): global_load_lds K/V dbuf,
// 1 barrier/iter, in-register P via cvt_pk+permlane32_swap (DISTINCT operands
// only — R3 pitfall), setprio. Stagger removed (R4: neutral).
// grid (32 qtiles, 4 chunks, NB), 256 threads.
// ---------------------------------------------------------------------------
__global__ __launch_bounds__(256, 2) void k_attn(const _Float16* __restrict__ Q,
                                                 const _Float16* __restrict__ K,
                                                 const _Float16* __restrict__ Vt,
                                                 _Float16* __restrict__ Opart,
                                                 float2* __restrict__ Ml) {
  __shared__ _Float16 smem[8192 * 4];  // K dbuf 32KB | V dbuf 32KB
  const int tid = threadIdx.x;
  const int wave = tid >> 6, lane = tid & 63;

  const int qt = blockIdx.x, ck = blockIdx.y, b = blockIdx.z;
  const int ql = lane & 31, h = lane >> 5;
  const int q0 = qt * 128 + wave * 32;
  const _Float16* Qb = Q + (size_t)b * NN * CC;
  const _Float16* Kg = K + (size_t)b * NN * CC;
  const _Float16* Vg = Vt + (size_t)b * NN * CC;
  const int kt_base = ck * KITERS;
  const int so = wave * 512;             // per-wave LDS stage base (halves)
  const int go = wave * 512 + lane * 8;  // per-lane global offset (halves)

  const int ktq = q0 >> 5;
  half8 qf[16];
#pragma unroll
  for (int cs = 0; cs < 16; cs++)
    qf[cs] = *(const half8*)(Qb + ((size_t)(ktq * 16 + cs) * 64 + lane) * 8);

  float16v Oa[8];
#pragma unroll
  for (int g = 0; g < 8; g++)
#pragma unroll
    for (int i = 0; i < 16; i++) Oa[g][i] = 0.f;

  float m_run = -1e30f, l_run = 0.f;
  half8 pf0, pf1;  // previous-iter P fragments, live in registers
#pragma unroll
  for (int i = 0; i < 8; i++) { pf0[i] = (_Float16)0.f; pf1[i] = (_Float16)0.f; }

  // prologue: stage K[0] -> Kbuf0
  {
    const _Float16* Kt = Kg + (size_t)kt_base * 8192;
#pragma unroll
    for (int p = 0; p < 4; p++) a16(Kt + p * 2048 + go, smem + p * 2048 + so);
  }

  for (int t = 0; t < KITERS; t++) {
    asm volatile("s_waitcnt vmcnt(0)" ::: "memory");  // K[t] (+V[t-1]) landed
    __builtin_amdgcn_s_barrier();
    // stage V[t] -> Vbuf[t&1]; K[t+1] -> Kbuf[(t+1)&1]
    {
      const _Float16* Vtile = Vg + (size_t)(kt_base + t) * 8192;
      _Float16* Vw = smem + (2 + (t & 1)) * 8192;
#pragma unroll
      for (int p = 0; p < 4; p++) a16(Vtile + p * 2048 + go, Vw + p * 2048 + so);
      if (t + 1 < KITERS) {
        const _Float16* Kt = Kg + (size_t)(kt_base + t + 1) * 8192;
        _Float16* Kw = smem + ((t + 1) & 1) * 8192;
#pragma unroll
        for (int p = 0; p < 4; p++) a16(Kt + p * 2048 + go, Kw + p * 2048 + so);
      }
    }
    const _Float16* Kl = smem + (t & 1) * 8192;

    // ---- MFMA burst: S_i and PV_i interleaved; PV in ks-outer order:
    //   i<8: Oa[i]   += V[2i]  ·pf0     i>=8: Oa[i-8] += V[2(i-8)+1]·pf1
    float16v s, s2;
#pragma unroll
    for (int i = 0; i < 16; i++) { s[i] = 0.f; s2[i] = 0.f; }
    __builtin_amdgcn_s_setprio(1);
    if (t > 0) {
      const _Float16* Vr = smem + (2 + ((t - 1) & 1)) * 8192;
#pragma unroll
      for (int i = 0; i < 16; i++) {
        half8 kf = *(const half8*)(Kl + i * 512 + lane * 8);
        if (i & 1)
          s2 = __builtin_amdgcn_mfma_f32_32x32x16_f16(kf, qf[i], s2, 0, 0, 0);
        else
          s = __builtin_amdgcn_mfma_f32_32x32x16_f16(kf, qf[i], s, 0, 0, 0);
        const int u = i & 7, ks = i >> 3;
        half8 vf = *(const half8*)(Vr + (2 * u + ks) * 512 + lane * 8);
        Oa[u] = __builtin_amdgcn_mfma_f32_32x32x16_f16(vf, ks ? pf1 : pf0, Oa[u], 0, 0, 0);
      }
    } else {
#pragma unroll
      for (int cs = 0; cs < 16; cs += 2) {
        half8 kfa = *(const half8*)(Kl + cs * 512 + lane * 8);
        s = __builtin_amdgcn_mfma_f32_32x32x16_f16(kfa, qf[cs], s, 0, 0, 0);
        half8 kfb = *(const half8*)(Kl + (cs + 1) * 512 + lane * 8);
        s2 = __builtin_amdgcn_mfma_f32_32x32x16_f16(kfb, qf[cs + 1], s2, 0, 0, 0);
      }
    }
    __builtin_amdgcn_s_setprio(0);
#pragma unroll
    for (int i = 0; i < 16; i++) s[i] += s2[i];

    // ---- lazy online softmax (per-lane), tree reductions
    float t0 = fmaxf(s[0], s[1]), t1 = fmaxf(s[2], s[3]);
    float t2 = fmaxf(s[4], s[5]), t3 = fmaxf(s[6], s[7]);
    float t4 = fmaxf(s[8], s[9]), t5 = fmaxf(s[10], s[11]);
    float t6 = fmaxf(s[12], s[13]), t7 = fmaxf(s[14], s[15]);
    t0 = fmaxf(t0, t1); t2 = fmaxf(t2, t3); t4 = fmaxf(t4, t5); t6 = fmaxf(t6, t7);
    float tmax = fmaxf(fmaxf(t0, t2), fmaxf(t4, t6));
    tmax = fmaxf(tmax, __shfl_xor(tmax, 32));
    bool need = tmax > m_run + 8.0f;
    if (__any((int)need)) {
      float mN = need ? tmax : m_run;
      float alpha = __expf(m_run - mN);
      m_run = mN;
      l_run *= alpha;
#pragma unroll
      for (int g = 0; g < 8; g++)
#pragma unroll
        for (int i = 0; i < 16; i++) Oa[g][i] *= alpha;
    }
#pragma unroll
    for (int i = 0; i < 16; i++) s[i] = __expf(s[i] - m_run);
    float u0 = (s[0] + s[1]) + (s[2] + s[3]);
    float u1 = (s[4] + s[5]) + (s[6] + s[7]);
    float u2 = (s[8] + s[9]) + (s[10] + s[11]);
    float u3 = (s[12] + s[13]) + (s[14] + s[15]);
    float ts = (u0 + u1) + (u2 + u3);
    ts += __shfl_xor(ts, 32);
    l_run += ts;

    // ---- P -> registers: pack f16 pairs, swap halves across lane 32 boundary.
    {
      int A01 = packh2(s[0], s[1]), B23 = packh2(s[2], s[3]);
      int C45 = packh2(s[4], s[5]), D67 = packh2(s[6], s[7]);
      int E01 = packh2(s[8], s[9]), F23 = packh2(s[10], s[11]);
      int G45 = packh2(s[12], s[13]), H67 = packh2(s[14], s[15]);
      auto rA = __builtin_amdgcn_permlane32_swap(A01, C45, false, false);
      auto rB = __builtin_amdgcn_permlane32_swap(B23, D67, false, false);
      auto rC = __builtin_amdgcn_permlane32_swap(E01, G45, false, false);
      auto rD = __builtin_amdgcn_permlane32_swap(F23, H67, false, false);
      intx4 w0, w1;
      w0[0] = rA[0]; w0[1] = rB[0]; w0[2] = rA[1]; w0[3] = rB[1];
      w1[0] = rC[0]; w1[1] = rD[0]; w1[2] = rC[1]; w1[3] = rD[1];
      pf0 = __builtin_bit_cast(half8, w0);
      pf1 = __builtin_bit_cast(half8, w1);
    }
  }

  // ---- tail: PV for last tile (ks-outer, same per-chain order)
  asm volatile("s_waitcnt vmcnt(0)" ::: "memory");  // V[KITERS-1] landed
  __builtin_amdgcn_s_barrier();
  {
    const _Float16* Vr = smem + (2 + ((KITERS - 1) & 1)) * 8192;
#pragma unroll
    for (int u = 0; u < 8; u++) {
      half8 vfa = *(const half8*)(Vr + (2 * u) * 512 + lane * 8);
      Oa[u] = __builtin_amdgcn_mfma_f32_32x32x16_f16(vfa, pf0, Oa[u], 0, 0, 0);
    }
#pragma unroll
    for (int u = 0; u < 8; u++) {
      half8 vfb = *(const half8*)(Vr + (2 * u + 1) * 512 + lane * 8);
      Oa[u] = __builtin_amdgcn_mfma_f32_32x32x16_f16(vfb, pf1, Oa[u], 0, 0, 0);
    }
  }

  // ---- epilogue: normalize, per-wave LDS transpose, coalesced store
  float invl = 1.f / l_run;
  __syncthreads();
  float* ot = (float*)smem + wave * (32 * 33);
  _Float16* Opb = Opart + ((size_t)ck * NB + b) * NN * CC;
  const int qr = lane >> 1;
  const int chalf = (lane & 1) * 16;
#pragma unroll
  for (int g = 0; g < 8; g++) {
#pragma unroll
    for (int r = 0; r < 16; r++)
      ot[((r & 3) + 8 * (r >> 2) + 4 * h) * 33 + ql] = Oa[g][r] * invl;
    __builtin_amdgcn_s_waitcnt(WAIT_LGKM0);
    half8 o0, o1;
#pragma unroll
    for (int i = 0; i < 8; i++) o0[i] = (_Float16)ot[(chalf + i) * 33 + qr];
#pragma unroll
    for (int i = 0; i < 8; i++) o1[i] = (_Float16)ot[(chalf + 8 + i) * 33 + qr];
    _Float16* gp = Opb + (size_t)(q0 + qr) * CC + g * 32 + chalf;
    *(half8*)gp = o0;
    *(half8*)(gp + 8) = o1;
    __builtin_amdgcn_s_waitcnt(WAIT_LGKM0);
  }
  if (h == 0) {
    float2 ml; ml.x = m_run; ml.y = l_run;
    Ml[((size_t)ck * NB + b) * NN + q0 + ql] = ml;
  }
}

// ---------------------------------------------------------------------------
// Final conv with fused split-K merge. v14: K-step 32 -> 64.
// Halves iterations (8->4) and barriers (16->8); 16 MFMA/wave per phase.
// Merge math element-identical, per-acc MFMA chain order identical
// (ks=0 then ks=1 == old kk then kk+32) -> bit-exact vs v13.
// out[b][d][n] fp32 = Wo . O^T + bo. grid (128, NB), 256 threads, 2 blocks/CU
// (LDS 27.6 KB).
// ---------------------------------------------------------------------------
__global__ __launch_bounds__(256, 2) void k_out(const _Float16* __restrict__ Opart,
                                                const float2* __restrict__ Ml,
                                                const float* __restrict__ Wo,
                                                const float* __restrict__ bo,
                                                float* __restrict__ out) {
  __shared__ _Float16 As[64][72];    // 9 KB   (merged O rows, 64-c slice)
  __shared__ _Float16 Bs[128][72];   // 18 KB  (Wo rows, 64-c slice)
  const int bz = blockIdx.y;
  const int mt = blockIdx.x >> 1, nt = blockIdx.x & 1;  // 64 mtiles x 2 ntiles
  const int m0 = mt * 64, n0 = nt * 128;
  const int tid = threadIdx.x;
  const int wave = tid >> 6, lane = tid & 63, quad = lane >> 4, l15 = lane & 15;
  const int wn = wave * 32;

  floatx4 acc[4][2];
#pragma unroll
  for (int i = 0; i < 4; i++)
#pragma unroll
    for (int j = 0; j < 2; j++) acc[i][j] = (floatx4){0.f, 0.f, 0.f, 0.f};

  const int arow = tid >> 2, acol = (tid & 3) * 16;   // A: 64 rows x 64 c
  const int brow = tid >> 1, bcol = (tid & 1) * 32;   // B: 128 rows x 64 c

  // merge weights for this thread's fixed row q = m0 + arow
  const size_t qi = (size_t)bz * NN + m0 + arow;
  float2 a0 = Ml[qi], a1 = Ml[(size_t)NB * NN + qi];
  float2 a2 = Ml[(size_t)2 * NB * NN + qi], a3 = Ml[(size_t)3 * NB * NN + qi];
  float M = fmaxf(fmaxf(a0.x, a1.x), fmaxf(a2.x, a3.x));
  float w0 = __expf(a0.x - M) * a0.y, w1 = __expf(a1.x - M) * a1.y;
  float w2 = __expf(a2.x - M) * a2.y, w3 = __expf(a3.x - M) * a3.y;
  float inv = 1.f / (w0 + w1 + w2 + w3);
  w0 *= inv; w1 *= inv; w2 *= inv; w3 *= inv;
  const size_t ps = (size_t)NB * NN * CC;
  const _Float16* prow = Opart + qi * CC;

  // preload kk=0: 4 planes x 2 half-slices of O, 8 float4 of Wo
  half8 pA[4][2];
  float4 wr[8];
  {
    const _Float16* pr = prow + acol;
#pragma unroll
    for (int pl = 0; pl < 4; pl++) {
      pA[pl][0] = *(const half8*)(pr + (size_t)pl * ps);
      pA[pl][1] = *(const half8*)(pr + (size_t)pl * ps + 8);
    }
    const float4* wp = (const float4*)(Wo + (size_t)(n0 + brow) * 256 + bcol);
#pragma unroll
    for (int i = 0; i < 8; i++) wr[i] = wp[i];
  }

  for (int kk = 0; kk < 256; kk += 64) {
    half8 ma0, ma1;
#pragma unroll
    for (int i = 0; i < 8; i++) {
      ma0[i] = (_Float16)(w0 * (float)pA[0][0][i] + w1 * (float)pA[1][0][i] +
                          w2 * (float)pA[2][0][i] + w3 * (float)pA[3][0][i]);
      ma1[i] = (_Float16)(w0 * (float)pA[0][1][i] + w1 * (float)pA[1][1][i] +
                          w2 * (float)pA[2][1][i] + w3 * (float)pA[3][1][i]);
    }
    half8 bl0, bh0, bl1, bh1;
    cvt16v(wr[0], wr[1], wr[2], wr[3], bl0, bh0);
    cvt16v(wr[4], wr[5], wr[6], wr[7], bl1, bh1);
    __syncthreads();  // prev frag reads done
    *(half8*)&As[arow][acol] = ma0;
    *(half8*)&As[arow][acol + 8] = ma1;
    *(half8*)&Bs[brow][bcol] = bl0;
    *(half8*)&Bs[brow][bcol + 8] = bh0;
    *(half8*)&Bs[brow][bcol + 16] = bl1;
    *(half8*)&Bs[brow][bcol + 24] = bh1;
    __syncthreads();  // tiles visible
    if (kk + 64 < 256) {  // prefetch next slice (in flight across MFMA phase)
      const _Float16* pr = prow + kk + 64 + acol;
#pragma unroll
      for (int pl = 0; pl < 4; pl++) {
        pA[pl][0] = *(const half8*)(pr + (size_t)pl * ps);
        pA[pl][1] = *(const half8*)(pr + (size_t)pl * ps + 8);
      }
      const float4* wp = (const float4*)(Wo + (size_t)(n0 + brow) * 256 + kk + 64 + bcol);
#pragma unroll
      for (int i = 0; i < 8; i++) wr[i] = wp[i];
    }
#pragma unroll
    for (int ks = 0; ks < 2; ks++) {
      half8 af[4], bfr[2];
#pragma unroll
      for (int mb = 0; mb < 4; mb++)
        af[mb] = *(const half8*)&As[mb * 16 + l15][ks * 32 + quad * 8];
#pragma unroll
      for (int nb = 0; nb < 2; nb++)
        bfr[nb] = *(const half8*)&Bs[wn + nb * 16 + l15][ks * 32 + quad * 8];
#pragma unroll
      for (int mb = 0; mb < 4; mb++)
#pragma unroll
        for (int nb = 0; nb < 2; nb++)
          acc[mb][nb] = __builtin_amdgcn_mfma_f32_16x16x32_f16(af[mb], bfr[nb], acc[mb][nb], 0, 0, 0);
    }
  }

  float* op = out + (size_t)bz * NN * CC;
#pragma unroll
  for (int mb = 0; mb < 4; mb++) {
    int nq0 = m0 + mb * 16 + quad * 4;  // spatial
#pragma unroll
    for (int nb = 0; nb < 2; nb++) {
      int d = n0 + wn + nb * 16 + l15;
      float bv = bo[d];
      floatx4 pk;
      pk[0] = acc[mb][nb][0] + bv;
      pk[1] = acc[mb][nb][1] + bv;
      pk[2] = acc[mb][nb][2] + bv;
      pk[3] = acc[mb][nb][3] + bv;
      *(floatx4*)(op + (size_t)d * NN + nq0) = pk;
    }
  }
}

// ---------------------------------------------------------------------------
extern "C" void kernel_launch(void* const* d_in, const int* in_sizes, int n_in,
                              void* d_out, int out_size, void* d_ws, size_t ws_size,
                              hipStream_t stream) {
  const float* Fc = (const float*)d_in[0];
  const float* Fs = (const float*)d_in[1];
  const float* Wf = (const float*)d_in[2];
  const float* bf_ = (const float*)d_in[3];
  const float* Wg = (const float*)d_in[4];
  const float* bg = (const float*)d_in[5];
  const float* Wh = (const float*)d_in[6];
  const float* bh = (const float*)d_in[7];
  const float* Wo = (const float*)d_in[8];
  const float* bo = (const float*)d_in[9];

  char* ws = (char*)d_ws;
  const size_t sz = (size_t)NB * NN * CC * sizeof(_Float16);  // 8 MB per plane
  _Float16* Opart = (_Float16*)(ws + 0 * sz);  // planes 0..3 (split-K partials)
  _Float16* Qs = (_Float16*)(ws + 4 * sz);     // swizzled
  _Float16* Ks = (_Float16*)(ws + 5 * sz);
  _Float16* Vs = (_Float16*)(ws + 6 * sz);
  float2* Ml = (float2*)(ws + 7 * sz);         // 512 KB

  k_qkv<<<dim3(64, NB, 3), 256, 0, stream>>>(Fc, Fs, Wf, Wg, Wh, bf_, bg, bh, Qs, Ks, Vs);
  k_attn<<<dim3(32, 4, NB), 256, 0, stream>>>(Qs, Ks, Vs, Opart, Ml);
  k_out<<<dim3(128, NB), 256, 0, stream>>>(Opart, Ml, Wo, bo, (float*)d_out);
}